// Round 7
// baseline (142.963 us; speedup 1.0000x reference)
//
#include <hip/hip_runtime.h>
#include <hip/hip_bf16.h>
#include <hip/hip_fp16.h>
#include <cstddef>
#include <cstdint>

#define BIGV 10000000.0f
#define WPV  1.0f

#define BATCH 8
#define T1N 256
#define T2N 1024
#define CN 128
#define DN 1279          // T1+T2-1

#define FLAG_MAGIC 0x600D0000

typedef __attribute__((ext_vector_type(2))) _Float16 half2v;

// ---------------------------------------------------------------------------
// Kernel 1 (R19, unchanged): cost with F16 LDS staging + packed math.
// ---------------------------------------------------------------------------
__global__ __launch_bounds__(256) void cost_kernel(const float* __restrict__ A,
                                                   const float* __restrict__ Bf,
                                                   const int* __restrict__ lenA,
                                                   const int* __restrict__ lenB,
                                                   float* __restrict__ sk) {
    __shared__ char As[64 * 256];     // 64 rows x 128 f16 ch  (16,384 B)
    __shared__ char Bs[127 * 256];    // 127 rows x 128 f16 ch (32,512 B)

    const int b  = blockIdx.z;
    const int d0 = blockIdx.y * 64;
    const int j0 = blockIdx.x * 64;
    const int tid = threadIdx.x;

    const int dEnd = lenA[b] + lenB[b] - 2;
    if (d0 > dEnd) return;            // rows never consumed

    const float* Ab = A  + (size_t)b * T1N * CN;
    const float* Bb = Bf + (size_t)b * T2N * CN;

    const int tj = tid & 15;
    const int td = tid >> 4;
    const int brow0 = td - tj + 63;   // rows brow0+16(m-3) in [0,126]
    const int rbase = d0 - j0 - 63;

    // swizzled byte offset: row stride 256B; 16B groups rotated by row
#define SWB(row, g) (((row) << 8) + ((((g) + (row)) & 15) << 4))

    // ---- stage A: 64 rows x 32 f32-quads = 2048 -> 8 per thread ----
    #pragma unroll
    for (int i = 0; i < 8; ++i) {
        int idx = tid + i * 256;
        int row = idx >> 5;
        int q   = idx & 31;               // channels 4q..4q+3
        float4 f = *(const float4*)(Ab + (size_t)(j0 + row) * CN + (q << 2));
        half2v h0 = { (_Float16)f.x, (_Float16)f.y };
        half2v h1 = { (_Float16)f.z, (_Float16)f.w };
        char* dst = As + SWB(row, q >> 1) + ((q & 1) << 3);
        ((uint32_t*)dst)[0] = __builtin_bit_cast(uint32_t, h0);
        ((uint32_t*)dst)[1] = __builtin_bit_cast(uint32_t, h1);
    }
    // ---- stage B: 127 rows x 32 quads = 4064 -> 16 per thread (guarded) ----
    #pragma unroll
    for (int i = 0; i < 16; ++i) {
        int idx = tid + i * 256;
        if (idx < 4064) {
            int row = idx >> 5;
            int q   = idx & 31;
            int gr = rbase + row;
            gr = gr < 0 ? 0 : (gr > T2N - 1 ? T2N - 1 : gr);
            float4 f = *(const float4*)(Bb + (size_t)gr * CN + (q << 2));
            half2v h0 = { (_Float16)f.x, (_Float16)f.y };
            half2v h1 = { (_Float16)f.z, (_Float16)f.w };
            char* dst = Bs + SWB(row, q >> 1) + ((q & 1) << 3);
            ((uint32_t*)dst)[0] = __builtin_bit_cast(uint32_t, h0);
            ((uint32_t*)dst)[1] = __builtin_bit_cast(uint32_t, h1);
        }
    }
    __syncthreads();

    float acc[4][4];
    #pragma unroll
    for (int i = 0; i < 4; ++i)
        #pragma unroll
        for (int j = 0; j < 4; ++j) acc[i][j] = 0.0f;

    const half2v one2 = { (_Float16)1.0f, (_Float16)1.0f };

    for (int g = 0; g < 16; ++g) {        // 8 channels per group
        uint4 a4[4], bv[7];
        #pragma unroll
        for (int ji = 0; ji < 4; ++ji) {
            int row = tj + 16 * ji;
            a4[ji] = *(const uint4*)(As + SWB(row, g));
        }
        #pragma unroll
        for (int m = 0; m < 7; ++m) {
            int row = brow0 + 16 * (m - 3);
            bv[m] = *(const uint4*)(Bs + SWB(row, g));
        }
        #pragma unroll
        for (int dk = 0; dk < 4; ++dk) {
            #pragma unroll
            for (int ji = 0; ji < 4; ++ji) {
                uint4 au = a4[ji];
                uint4 bu = bv[dk - ji + 3];
                float a = acc[dk][ji];
                #pragma unroll
                for (int w = 0; w < 4; ++w) {
                    uint32_t ua = (&au.x)[w];
                    uint32_t ub = (&bu.x)[w];
                    half2v d2 = __builtin_bit_cast(half2v, ua)
                              - __builtin_bit_cast(half2v, ub);
                    uint32_t du = __builtin_bit_cast(uint32_t, d2) & 0x7FFF7FFFu;
#if __has_builtin(__builtin_amdgcn_fdot2)
                    a = __builtin_amdgcn_fdot2(__builtin_bit_cast(half2v, du),
                                               one2, a, false);
#else
                    half2v ad = __builtin_bit_cast(half2v, du);
                    a += (float)ad.x + (float)ad.y;
#endif
                }
                acc[dk][ji] = a;
            }
        }
    }
#undef SWB

    #pragma unroll
    for (int dk = 0; dk < 4; ++dk) {
        int d = d0 + td + 16 * dk;
        if (d < DN) {
            size_t rowoff = ((size_t)b * DN + d) * T1N;
            #pragma unroll
            for (int ji = 0; ji < 4; ++ji) {
                int j = j0 + tj + 16 * ji;
                sk[rowoff + j] = acc[dk][ji] * (1.0f / 128.0f);
            }
        }
    }
}

// ---------------------------------------------------------------------------
// Kernel 2 (R24): dp, single-wave LDS-ring prefetch via global_load_lds.
// R23 post-mortem: VGPR_Count=112 proves the compiler sank the 192-VGPR
// register prefetch buffers -> window collapsed -> 55us (worse). Fix: the
// prefetch buffer is LDS, filled by global_load_lds DMA (zero VGPR cost,
// compiler can't shrink it). Counted vmcnt discipline (T4): issue blocks
// k..k+2 at start (48 loads <= 63 cap); per block: vmcnt(32) [block k
// landed] -> 16x ds_read_b128 -> lgkmcnt(0) fence (data in regs BEFORE
// slot k%3 is reused) -> issue block k+3 into that slot -> 16 ping-pong
// DP steps (R23b math, verified absmax 0.0). Epilogue waits 32/16/0,
// never draining mid-loop. Ring 3 x 16KB = 48KB LDS. ~650cy/block model
// -> predict dp 24-30us (was 55.4).
// ---------------------------------------------------------------------------
__device__ __forceinline__ float min3f(float a, float b, float c) {
    float d;
    asm("v_min3_f32 %0, %1, %2, %3" : "=v"(d) : "v"(a), "v"(b), "v"(c));
    return d;
}

__global__ __launch_bounds__(64, 1) void dp_lds_kernel(const float* __restrict__ sk,
                                                       const int* __restrict__ lenA,
                                                       const int* __restrict__ lenB,
                                                       float* __restrict__ partials,
                                                       int* __restrict__ flags,
                                                       float* __restrict__ out) {
    __shared__ char ring[3 * 16384];      // 3 slots x 16 rows x 1KB

    const int b = blockIdx.x;
    const int L = threadIdx.x;            // 0..63, columns 4L..4L+3

    const int la = __builtin_amdgcn_readfirstlane(lenA[b]);
    const int lb = __builtin_amdgcn_readfirstlane(lenB[b]);
    const int dEnd = la + lb - 2;         // in [638, 1278]
    const int kLast = dEnd >> 4;          // in [39, 79]

    // per-lane global source: lane L covers bytes [L*16, L*16+16) of each row
    const float* skb = sk + (size_t)b * DN * T1N + (L << 2);

    char* s0 = ring;
    char* s1 = ring + 16384;
    char* s2 = ring + 32768;

    // DP state: x = row d-1, y = row d-2 at every block boundary.
    float x0 = BIGV, x1 = BIGV, x2 = BIGV, x3 = BIGV;
    float y0 = BIGV, y1 = BIGV, y2 = BIGV, y3 = BIGV;
    float pp = (L == 0) ? 0.0f : BIGV;    // shfl-carry; seeds pcp0 col-0 = 0

#define SHFL_UP1(SRC)                                                       \
    __int_as_float(__builtin_amdgcn_update_dpp(                             \
        __float_as_int(BIGV), __float_as_int(SRC),                          \
        0x138 /* wave_shr:1 */, 0xF, 0xF, false))

#define WAITV(N) do {                                                       \
        asm volatile("s_waitcnt vmcnt(" #N ")" ::: "memory");               \
        __builtin_amdgcn_sched_barrier(0);                                  \
    } while (0)

#define WAITL0 do {                                                         \
        asm volatile("s_waitcnt lgkmcnt(0)" ::: "memory");                  \
        __builtin_amdgcn_sched_barrier(0);                                  \
    } while (0)

    // issue one 16-row block into slot SL (DMA: no VGPR buffer).
    // row clamp to DN-1 keeps b=7's tail block inside the workspace.
#define ISSUE(KB, SL) do {                                                  \
        _Pragma("unroll")                                                   \
        for (int r_ = 0; r_ < 16; ++r_) {                                   \
            int row_ = ((KB) << 4) + r_;                                    \
            row_ = row_ > DN - 1 ? DN - 1 : row_;                           \
            __builtin_amdgcn_global_load_lds(                               \
                (const __attribute__((address_space(1))) void*)(skb + (size_t)row_ * T1N), \
                (__attribute__((address_space(3))) void*)((SL) + (r_ << 10)), \
                16, 0, 0);                                                  \
        }                                                                   \
    } while (0)

#define READ16(SL)                                                          \
        float4 cc0  = *(const float4*)((SL) +  0 * 1024 + (L << 4));        \
        float4 cc1  = *(const float4*)((SL) +  1 * 1024 + (L << 4));        \
        float4 cc2  = *(const float4*)((SL) +  2 * 1024 + (L << 4));        \
        float4 cc3  = *(const float4*)((SL) +  3 * 1024 + (L << 4));        \
        float4 cc4  = *(const float4*)((SL) +  4 * 1024 + (L << 4));        \
        float4 cc5  = *(const float4*)((SL) +  5 * 1024 + (L << 4));        \
        float4 cc6  = *(const float4*)((SL) +  6 * 1024 + (L << 4));        \
        float4 cc7  = *(const float4*)((SL) +  7 * 1024 + (L << 4));        \
        float4 cc8  = *(const float4*)((SL) +  8 * 1024 + (L << 4));        \
        float4 cc9  = *(const float4*)((SL) +  9 * 1024 + (L << 4));        \
        float4 cc10 = *(const float4*)((SL) + 10 * 1024 + (L << 4));        \
        float4 cc11 = *(const float4*)((SL) + 11 * 1024 + (L << 4));        \
        float4 cc12 = *(const float4*)((SL) + 12 * 1024 + (L << 4));        \
        float4 cc13 = *(const float4*)((SL) + 13 * 1024 + (L << 4));        \
        float4 cc14 = *(const float4*)((SL) + 14 * 1024 + (L << 4));        \
        float4 cc15 = *(const float4*)((SL) + 15 * 1024 + (L << 4));

    // P = row d-1 regs, Q = row d-2 regs; writes row d INTO Q (d-2 is dead).
#define DPP_STEP(C4, P, Q) do {                                             \
        float4 c_ = (C4);                                                   \
        float p1_ = SHFL_UP1(P##3);                                         \
        float w0_ = P##0 + WPV, w1_ = P##1 + WPV;                           \
        float w2_ = P##2 + WPV, w3_ = P##3 + WPV;                           \
        float wp_ = p1_ + WPV;                                              \
        float t0_ = c_.x + min3f(pp, w0_, wp_);                             \
        float t1_ = c_.y + min3f(Q##0, w1_, w0_);                           \
        float t2_ = c_.z + min3f(Q##1, w2_, w1_);                           \
        float t3_ = c_.w + min3f(Q##2, w3_, w2_);                           \
        pp = p1_;                                                           \
        Q##0 = t0_; Q##1 = t1_; Q##2 = t2_; Q##3 = t3_;                     \
    } while (0)

    // 16 steps = even count -> roles return to (x=d-1, y=d-2) at block end.
#define COMPUTE16 do {                                                      \
        DPP_STEP(cc0,  x, y); DPP_STEP(cc1,  y, x);                         \
        DPP_STEP(cc2,  x, y); DPP_STEP(cc3,  y, x);                         \
        DPP_STEP(cc4,  x, y); DPP_STEP(cc5,  y, x);                         \
        DPP_STEP(cc6,  x, y); DPP_STEP(cc7,  y, x);                         \
        DPP_STEP(cc8,  x, y); DPP_STEP(cc9,  y, x);                         \
        DPP_STEP(cc10, x, y); DPP_STEP(cc11, y, x);                         \
        DPP_STEP(cc12, x, y); DPP_STEP(cc13, y, x);                         \
        DPP_STEP(cc14, x, y); DPP_STEP(cc15, y, x);                         \
    } while (0)

#define GSTEP(C4, PN, QN, R) do { if ((R) <= rem) DPP_STEP(C4, PN, QN); } while (0)
#define GUARD16 do {                                                        \
        GSTEP(cc0,  x, y, 0);  GSTEP(cc1,  y, x, 1);                        \
        GSTEP(cc2,  x, y, 2);  GSTEP(cc3,  y, x, 3);                        \
        GSTEP(cc4,  x, y, 4);  GSTEP(cc5,  y, x, 5);                        \
        GSTEP(cc6,  x, y, 6);  GSTEP(cc7,  y, x, 7);                        \
        GSTEP(cc8,  x, y, 8);  GSTEP(cc9,  y, x, 9);                        \
        GSTEP(cc10, x, y, 10); GSTEP(cc11, y, x, 11);                       \
        GSTEP(cc12, x, y, 12); GSTEP(cc13, y, x, 13);                       \
        GSTEP(cc14, x, y, 14); GSTEP(cc15, y, x, 15);                       \
    } while (0)

    // prologue: blocks 0..2 in flight (48 outstanding <= vmcnt cap 63)
    ISSUE(0, s0);
    ISSUE(1, s1);
    ISSUE(2, s2);

    // main loop: k <= kLast-3, so issue k+3 <= kLast is always valid
    int k = 0;
    for (; k + 2 < kLast; ++k) {
        WAITV(32);                        // block k's 16 loads landed in s0
        READ16(s0);
        WAITL0;                           // reads drained before slot reuse
        ISSUE(k + 3, s0);
        COMPUTE16;
        { char* t_ = s0; s0 = s1; s1 = s2; s2 = t_; }
    }

    // epilogue: k == kLast-2 .. kLast (blocks already issued; drain 32/16/0)
    {
        WAITV(32);
        READ16(s0);
        WAITL0;
        COMPUTE16;
        { char* t_ = s0; s0 = s1; s1 = s2; s2 = t_; }
    }
    {
        WAITV(16);
        READ16(s0);
        WAITL0;
        COMPUTE16;
        { char* t_ = s0; s0 = s1; s1 = s2; s2 = t_; }
    }
    const int rem = dEnd & 15;
    {
        WAITV(0);
        READ16(s0);
        GUARD16;
    }

    // final row lives in y if rem is even (last committed step writes y), else x
    float f0, f1, f2, f3;
    if ((rem & 1) == 0) { f0 = y0; f1 = y1; f2 = y2; f3 = y3; }
    else                { f0 = x0; f1 = x1; f2 = x2; f3 = x3; }

    // publish partials[b] with replay-safe magic flag (poison-robust)
    const int tcap = la - 1;
    if (L == (tcap >> 2)) {
        const int kk = tcap & 3;
        float r = f0;
        if (kk == 1) r = f1;
        else if (kk == 2) r = f2;
        else if (kk == 3) r = f3;
        partials[b] = r;
        __threadfence();
        __hip_atomic_store(&flags[b], FLAG_MAGIC + b,
                           __ATOMIC_RELEASE, __HIP_MEMORY_SCOPE_AGENT);
    }

    // block 0: gather all 8 partials and write the final sum
    if (b == 0 && L == 0) {
        float s = 0.0f;
        for (int i = 0; i < BATCH; ++i) {
            while (__hip_atomic_load(&flags[i], __ATOMIC_ACQUIRE,
                                     __HIP_MEMORY_SCOPE_AGENT) != FLAG_MAGIC + i)
                __builtin_amdgcn_s_sleep(2);
            s += __hip_atomic_load(&partials[i], __ATOMIC_RELAXED,
                                   __HIP_MEMORY_SCOPE_AGENT);
        }
        out[0] = s;
    }
#undef GUARD16
#undef GSTEP
#undef COMPUTE16
#undef DPP_STEP
#undef READ16
#undef ISSUE
#undef WAITL0
#undef WAITV
#undef SHFL_UP1
}

extern "C" void kernel_launch(void* const* d_in, const int* in_sizes, int n_in,
                              void* d_out, int out_size, void* d_ws, size_t ws_size,
                              hipStream_t stream) {
    const float* feaA = (const float*)d_in[0];
    const int*   lenA = (const int*)d_in[1];
    const float* feaB = (const float*)d_in[2];
    const int*   lenB = (const int*)d_in[3];

    float* sk       = (float*)d_ws;                       // 8*1279*256*4 B
    float* partials = (float*)((char*)d_ws + (size_t)BATCH * DN * T1N * sizeof(float));
    int*   flags    = (int*)(partials + BATCH);

    cost_kernel<<<dim3(T1N / 64, (DN + 63) / 64, BATCH), 256, 0, stream>>>(feaA, feaB, lenA, lenB, sk);
    dp_lds_kernel<<<BATCH, 64, 0, stream>>>(sk, lenA, lenB, partials, flags, (float*)d_out);
}